// Round 8
// baseline (182.457 us; speedup 1.0000x reference)
//
#include <hip/hip_runtime.h>
#include <hip/hip_fp16.h>

// TriMul (outgoing) pipeline, MI355X gfx950.
//  K0: Wimg = pre-swizzled LDS image of [Wp|Wg|Wgate] cols; W1t/s1/s2 fold LN-out
//  K2: fused LN(z) + proj GEMM h @ W^T + fast sigmoid -> a_t/b_t (k-slot
//      PRE-SWIZZLED for K3's BK=32 image), g_out. 128 rows/block, 8 waves,
//      LDS 53.5 KB -> 3 blocks/CU.
//  K3: batched einsum C_c = A_c*B_c^T, 256x256 tiles, BK=32 TRIPLE-buffered LDS,
//      2-tiles-ahead prefetch, counted vmcnt(8) (never drains mid-loop).
//  K4: stats + MFMA (raw mid @ W1) + affine LN correction + gate -> out fp32

typedef _Float16 half_t;
typedef _Float16 f16x4 __attribute__((ext_vector_type(4)));
typedef _Float16 f16x8 __attribute__((ext_vector_type(8)));
typedef float f32x4 __attribute__((ext_vector_type(4)));

#define NSEQ 512
#define HID 128
#define ROWS (NSEQ * NSEQ)   // 262144

#define GLOAD16(src, dst)                                                        \
    __builtin_amdgcn_global_load_lds(                                            \
        (const __attribute__((address_space(1))) void*)(src),                    \
        (__attribute__((address_space(3))) void*)(dst), 16, 0, 0)

__device__ __forceinline__ float fast_sigmoid(float x) {
    float e = __builtin_amdgcn_exp2f(-1.44269504088896f * x);
    return __builtin_amdgcn_rcpf(1.f + e);
}

// ---------------------------------------------------------------- K0: weights
__global__ void k_prep_w(const float* __restrict__ Wp, const float* __restrict__ Wg,
                         const float* __restrict__ Wgate,
                         const float* __restrict__ ln_out_w, const float* __restrict__ ln_out_b,
                         const float* __restrict__ Wout,
                         half_t* __restrict__ Wimg, half_t* __restrict__ W1t,
                         float* __restrict__ s1, float* __restrict__ s2) {
    int bid = blockIdx.x, t = threadIdx.x;
    if (bid < 18) {
        int chunk = bid * 256 + t;               // 4608 = 2 ch x 2304
        int ch = chunk >= 2304;
        int q = chunk - ch * 2304;
        int lr = q >> 3, slot = q & 7;
        int co = slot ^ (lr & 7);
        int grow;
        if (lr < 128)      grow = ch * 128 + lr;               // Wp cols
        else if (lr < 256) grow = 256 + ch * 128 + (lr - 128); // Wg cols
        else               grow = 512 + ch * 32 + (lr - 256);  // Wgate cols
        f16x8 vals;
        #pragma unroll
        for (int j = 0; j < 8; ++j) {
            int l = co * 8 + j;
            float v;
            if (grow < 256)      v = Wp[l * 256 + grow];
            else if (grow < 512) v = Wg[l * 256 + (grow - 256)];
            else                 v = Wgate[l * 64 + (grow - 512)];
            vals[j] = (half_t)v;
        }
        *(f16x8*)(Wimg + (size_t)chunk * 8) = vals;
    } else {
        // W1t[o][c] = ln_out_w[c] * Wout[c][o]   (64 x 128)
        #pragma unroll
        for (int i = 0; i < 32; ++i) {
            int idx = t * 32 + i;                // 8192
            int o = idx >> 7, c = idx & 127;
            W1t[idx] = (half_t)(ln_out_w[c] * Wout[c * 64 + o]);
        }
        if (t < 64) {
            float a1 = 0.f, a2 = 0.f;
            for (int c = 0; c < 128; ++c) {
                float wo = Wout[c * 64 + t];
                a1 += ln_out_w[c] * wo;
                a2 += ln_out_b[c] * wo;
            }
            s1[t] = a1; s2[t] = a2;
        }
    }
}

// ---------------------------------------------------------------- K2: fused LN + projections
// grid (2048, 2): x = 128-row block, y = half (0 -> a + gate[0..31], 1 -> b + gate[32..63])
// LDS 53504 B -> 3 blocks/CU. a_t/b_t written with BK=32 k-slot swizzle
// (image slot S holds logical s = S ^ ((i>>1)&3), i = position>>9).
__global__ __launch_bounds__(512) void k_proj(const float* __restrict__ z,
                                              const float* __restrict__ lnw,
                                              const float* __restrict__ lnb,
                                              const half_t* __restrict__ Wimg,
                                              half_t* __restrict__ a_t,
                                              half_t* __restrict__ b_t,
                                              half_t* __restrict__ g_out) {
    __shared__ half_t Wl[288 * 64];        // 36 KB, swizzled rows of 128B (image copy)
    __shared__ half_t pgl[64 * 130];       // 16640 B, [c&63][row] stride 130

    int t = threadIdx.x;
    int ch = blockIdx.y;
    int bx = blockIdx.x;
    int r0 = bx * 128;
    int wid = t >> 6, lane = t & 63;
    int m = lane & 15, g = lane >> 4;

    // stage weights via async DMA (image is pre-swizzled + linear): 2304 chunks
    const half_t* wsrc = Wimg + (size_t)ch * 2304 * 8;
    #pragma unroll
    for (int it = 0; it < 5; ++it) {
        int cb = it * 512 + wid * 64;      // wave-uniform chunk base
        if (cb < 2304)
            GLOAD16(wsrc + (size_t)(cb + lane) * 8, Wl + (size_t)cb * 8);
    }

    // fused LayerNorm: this lane's row p, dims {ks*32 + g*8 .. +8}
    int growbase = r0 + wid * 16;
    int p = growbase + m;
    f32x4 zv[4];
    #pragma unroll
    for (int ks = 0; ks < 2; ++ks) {
        zv[ks * 2]     = *(const f32x4*)(z + (size_t)p * 64 + ks * 32 + g * 8);
        zv[ks * 2 + 1] = *(const f32x4*)(z + (size_t)p * 64 + ks * 32 + g * 8 + 4);
    }
    float s = 0.f, s2 = 0.f;
    #pragma unroll
    for (int q = 0; q < 4; ++q)
        #pragma unroll
        for (int j = 0; j < 4; ++j) { float v = zv[q][j]; s += v; s2 += v * v; }
    s  += __shfl_xor(s, 16, 64);  s2 += __shfl_xor(s2, 16, 64);
    s  += __shfl_xor(s, 32, 64);  s2 += __shfl_xor(s2, 32, 64);
    float mu = s * (1.f / 64.f);
    float var = s2 * (1.f / 64.f) - mu * mu;
    float rs = rsqrtf(var + 1e-5f);
    f16x8 af[2];
    #pragma unroll
    for (int ks = 0; ks < 2; ++ks) {
        f32x4 w0 = *(const f32x4*)(lnw + ks * 32 + g * 8);
        f32x4 w1 = *(const f32x4*)(lnw + ks * 32 + g * 8 + 4);
        f32x4 b0 = *(const f32x4*)(lnb + ks * 32 + g * 8);
        f32x4 b1 = *(const f32x4*)(lnb + ks * 32 + g * 8 + 4);
        #pragma unroll
        for (int j = 0; j < 4; ++j) {
            af[ks][j]     = (half_t)((zv[ks * 2][j]     - mu) * rs * w0[j] + b0[j]);
            af[ks][4 + j] = (half_t)((zv[ks * 2 + 1][j] - mu) * rs * w1[j] + b1[j]);
        }
    }

    __syncthreads();   // drains gload_lds + all waves staged

    half_t* dst = (ch == 0) ? a_t : b_t;
    int swz = (bx >> 3) & 3;               // = (i>>1)&3, i = bx>>2

    // p/g pair tiles in 2 groups of 4; pgl holds 64 channels x 128 rows
    for (int grp = 0; grp < 2; ++grp) {
        #pragma unroll
        for (int pt4 = 0; pt4 < 4; ++pt4) {
            int pt = grp * 4 + pt4;
            f32x4 accp = {0.f, 0.f, 0.f, 0.f}, accg = {0.f, 0.f, 0.f, 0.f};
            #pragma unroll
            for (int ks = 0; ks < 2; ++ks) {
                int kb = (ks * 32 + g * 8) * 2;
                int lrp = pt * 16 + m;
                f16x8 bp = *(const f16x8*)((char*)Wl + lrp * 128 + (kb ^ ((lrp & 7) << 4)));
                int lrg = 128 + pt * 16 + m;
                f16x8 bg = *(const f16x8*)((char*)Wl + lrg * 128 + (kb ^ ((lrg & 7) << 4)));
                accp = __builtin_amdgcn_mfma_f32_16x16x32_f16(af[ks], bp, accp, 0, 0, 0);
                accg = __builtin_amdgcn_mfma_f32_16x16x32_f16(af[ks], bg, accg, 0, 0, 0);
            }
            f16x4 pk;
            #pragma unroll
            for (int r = 0; r < 4; ++r)
                pk[r] = (half_t)(accp[r] * fast_sigmoid(accg[r]));
            *(f16x4*)&pgl[(pt4 * 16 + m) * 130 + wid * 16 + g * 4] = pk;
        }
        __syncthreads();
        // flush 64 channels x 128 rows; k-slot swizzled for K3's BK=32 image
        #pragma unroll
        for (int it = 0; it < 2; ++it) {
            int chunk = it * 512 + t;      // 1024
            int cl = chunk >> 4, r16 = chunk & 15;
            f16x8 v = *(const f16x8*)&pgl[cl * 130 + r16 * 8];
            int dk = (r16 & 12) | ((r16 & 3) ^ swz);
            *(f16x8*)(dst + (size_t)(grp * 64 + cl) * ROWS + r0 + dk * 8) = v;
        }
        __syncthreads();
    }

    // gate tiles -> g_out[row][och] = sigmoid(h @ Wgate)
    for (int gt = 0; gt < 2; ++gt) {
        f32x4 acc = {0.f, 0.f, 0.f, 0.f};
        #pragma unroll
        for (int ks = 0; ks < 2; ++ks) {
            int kb = (ks * 32 + g * 8) * 2;
            int lr = 256 + gt * 16 + m;
            f16x8 bb = *(const f16x8*)((char*)Wl + lr * 128 + (kb ^ ((lr & 7) << 4)));
            acc = __builtin_amdgcn_mfma_f32_16x16x32_f16(af[ks], bb, acc, 0, 0, 0);
        }
        int och = ch * 32 + gt * 16 + m;
        #pragma unroll
        for (int r = 0; r < 4; ++r) {
            float og = fast_sigmoid(acc[r]);
            int grow = growbase + g * 4 + r;
            g_out[(size_t)grow * 64 + och] = (half_t)og;
        }
    }
}

// ---------------------------------------------------------------- K3: batched einsum
// 512 blocks x 512 threads; 256x256 tile, XCD-grouped; BK=32 TRIPLE-buffered
// global_load_lds pipeline, 2 tiles ahead, counted vmcnt(8) (8 loads always in
// flight at every wait). LDS read XOR: slot = g ^ ((row>>1)&3).
__global__ __launch_bounds__(512) void k_einsum(const half_t* __restrict__ a_t,
                                                const half_t* __restrict__ b_t,
                                                half_t* __restrict__ out_mid) {
    __shared__ half_t Al[3][256 * 32];   // 3 x 16 KB
    __shared__ half_t Bl[3][256 * 32];   // 3 x 16 KB  (96 KB total -> 1 block/CU)

    int t = threadIdx.x;
    int bid = blockIdx.x;
    int xcd = bid & 7, kk = bid >> 3;
    int c = xcd + 8 * (kk >> 2);
    int tt = kk & 3;
    int i0 = (tt & 1) * 256, j0 = (tt >> 1) * 256;

    const half_t* A = a_t + (size_t)c * ROWS;   // [i][k], k-slots pre-swizzled
    const half_t* B = b_t + (size_t)c * ROWS;   // [j][k]

    int wid = t >> 6, lane = t & 63;
    int m = lane & 15, g = lane >> 4;
    int wr = wid >> 2, wc = wid & 3;            // wave tile: 128 rows x 64 cols

    f32x4 acc[8][4] = {};

    // per K-step, per operand: 1024 chunks of 16B; 2 per thread (4 vmcnt events)
#define STAGE(ktt, Ab, Bb)                                                        \
    {                                                                             \
        _Pragma("unroll")                                                         \
        for (int rnd = 0; rnd < 2; ++rnd) {                                       \
            int cb = rnd * 512 + wid * 64;      /* wave-uniform chunk base */     \
            int chunk = cb + lane;                                                \
            int row = chunk >> 2, slot = chunk & 3;                               \
            GLOAD16(A + (size_t)(i0 + row) * 512 + (ktt) * 32 + slot * 8,         \
                    (Ab) + (size_t)cb * 8);                                       \
            GLOAD16(B + (size_t)(j0 + row) * 512 + (ktt) * 32 + slot * 8,         \
                    (Bb) + (size_t)cb * 8);                                       \
        }                                                                         \
    }

    STAGE(0, Al[0], Bl[0]);
    STAGE(1, Al[1], Bl[1]);

    int cur = 0;
    for (int kt = 0; kt < 16; ++kt) {
        if (kt < 14) {
            int nb = cur + 2; if (nb >= 3) nb -= 3;
            STAGE(kt + 2, Al[nb], Bl[nb]);
            // outstanding: kt(4, ~done) + kt+1(4) + kt+2(4); ensure kt complete
            asm volatile("s_waitcnt vmcnt(8)" ::: "memory");
        } else if (kt == 14) {
            asm volatile("s_waitcnt vmcnt(4)" ::: "memory");
        } else {
            asm volatile("s_waitcnt vmcnt(0)" ::: "memory");
        }
        __builtin_amdgcn_s_barrier();
        __builtin_amdgcn_sched_barrier(0);

        const half_t* Ac = Al[cur];
        const half_t* Bc = Bl[cur];
        f16x8 bf[4];
        #pragma unroll
        for (int ni = 0; ni < 4; ++ni) {
            int lrow = wc * 64 + ni * 16 + m;
            int so = (g ^ ((lrow >> 1) & 3)) * 16;
            bf[ni] = *(const f16x8*)((char*)Bc + lrow * 64 + so);
        }
        #pragma unroll
        for (int mi = 0; mi < 8; ++mi) {
            int lrow = wr * 128 + mi * 16 + m;
            int so = (g ^ ((lrow >> 1) & 3)) * 16;
            f16x8 afr = *(const f16x8*)((char*)Ac + lrow * 64 + so);
            #pragma unroll
            for (int ni = 0; ni < 4; ++ni)
                acc[mi][ni] = __builtin_amdgcn_mfma_f32_16x16x32_f16(afr, bf[ni], acc[mi][ni], 0, 0, 0);
        }
        __builtin_amdgcn_s_barrier();
        cur = (cur == 2) ? 0 : cur + 1;
    }
#undef STAGE

    half_t* O = out_mid + (size_t)c * ROWS;   // [i*512 + j]
    #pragma unroll
    for (int mi = 0; mi < 8; ++mi) {
        #pragma unroll
        for (int ni = 0; ni < 4; ++ni) {
            int row = i0 + wr * 128 + mi * 16 + g * 4;
            int col = j0 + wc * 64 + ni * 16 + m;
            #pragma unroll
            for (int r = 0; r < 4; ++r)
                O[(size_t)(row + r) * 512 + col] = (half_t)acc[mi][ni][r];
        }
    }
}

// ---------------------------------------------------------------- K4: folded LN + MFMA + gate
// out[p,o] = (rs_p*(x@W1)[o] - mu_p*rs_p*s1[o] + s2[o]) * gate[p,o]
__global__ __launch_bounds__(256) void k_final(const half_t* __restrict__ out_mid,
                                               const half_t* __restrict__ W1t,
                                               const float* __restrict__ s1g,
                                               const float* __restrict__ s2g,
                                               const half_t* __restrict__ g_out,
                                               float* __restrict__ out) {
    __shared__ half_t midl[128 * 64];   // [c][p] 16 KB linear
    __shared__ half_t midt[64 * 128];   // [p][c] 16 KB swizzled
    __shared__ half_t w1l[64 * 128];    // [o][c] 16 KB swizzled
    __shared__ half_t gl[64 * 72];      // [p][o] 9 KB padded
    __shared__ float smu[64], srs[64], s1l[64], s2l[64];

    int t = threadIdx.x;
    int pos0 = blockIdx.x * 64;

    #pragma unroll
    for (int it = 0; it < 4; ++it) {
        int chunk = it * 256 + t;       // 1024
        int cc = chunk >> 3, co = chunk & 7;
        *(uint4*)((char*)midl + cc * 128 + co * 16) =
            *(const uint4*)(out_mid + (size_t)cc * ROWS + pos0 + co * 8);
    }
    // w1l: 64 rows x 16 slots of 16B = 1024 chunks
    #pragma unroll
    for (int it = 0; it < 4; ++it) {
        int chunk = it * 256 + t;       // 1024
        int row = chunk >> 4, slot = chunk & 15;
        *(uint4*)((char*)w1l + row * 256 + ((slot * 16) ^ ((row & 7) << 4))) =
            *(const uint4*)(W1t + row * 128 + slot * 8);
    }
    #pragma unroll
    for (int it = 0; it < 2; ++it) {
        int chunk = it * 256 + t;       // 512
        int row = chunk >> 3, co = chunk & 7;
        *(uint4*)((char*)gl + row * 144 + co * 16) =
            *(const uint4*)(g_out + (size_t)(pos0 + row) * 64 + co * 8);
    }
    if (t < 64) { s1l[t] = s1g[t]; s2l[t] = s2g[t]; }
    __syncthreads();

    // transpose midl -> midt (swizzled) + per-position stats
    {
        int p = t >> 2, q = t & 3;
        float s = 0.f, s2 = 0.f;
        #pragma unroll
        for (int cc4 = 0; cc4 < 4; ++cc4) {
            f16x8 pack;
            #pragma unroll
            for (int j = 0; j < 8; ++j) {
                half_t hv = midl[(q * 32 + cc4 * 8 + j) * 64 + p];
                float v = (float)hv;
                s += v; s2 += v * v;
                pack[j] = hv;
            }
            int slot = q * 4 + cc4;
            *(f16x8*)((char*)midt + p * 256 + ((slot * 16) ^ ((p & 7) << 4))) = pack;
        }
        s  += __shfl_xor(s, 1, 64);  s  += __shfl_xor(s, 2, 64);
        s2 += __shfl_xor(s2, 1, 64); s2 += __shfl_xor(s2, 2, 64);
        if (q == 0) {
            float mu = s * (1.f / 128.f);
            float var = s2 * (1.f / 128.f) - mu * mu;
            smu[p] = mu;
            srs[p] = rsqrtf(var + 1e-5f);
        }
    }
    __syncthreads();

    int wid = t >> 6, lane = t & 63;
    int m = lane & 15, g = lane >> 4;

    f32x4 acc[4] = {};
    #pragma unroll
    for (int ks = 0; ks < 4; ++ks) {
        int arow = wid * 16 + m;
        f16x8 af = *(const f16x8*)((char*)midt + arow * 256 +
                                   (((4 * ks + g) * 16) ^ ((arow & 7) << 4)));
        #pragma unroll
        for (int ni = 0; ni < 4; ++ni) {
            int brow = ni * 16 + m;
            f16x8 bf = *(const f16x8*)((char*)w1l + brow * 256 +
                                       (((4 * ks + g) * 16) ^ ((brow & 7) << 4)));
            acc[ni] = __builtin_amdgcn_mfma_f32_16x16x32_f16(af, bf, acc[ni], 0, 0, 0);
        }
    }

    #pragma unroll
    for (int ni = 0; ni < 4; ++ni) {
        int o = ni * 16 + m;
        float v1 = s1l[o], v2 = s2l[o];
        #pragma unroll
        for (int r = 0; r < 4; ++r) {
            int lrow = wid * 16 + g * 4 + r;
            float mu = smu[lrow], rs = srs[lrow];
            float val = acc[ni][r] * rs - mu * rs * v1 + v2;
            float gate = (float)gl[lrow * 72 + o];
            out[(size_t)(pos0 + lrow) * 64 + o] = val * gate;
        }
    }
}

// ---------------------------------------------------------------- launch
extern "C" void kernel_launch(void* const* d_in, const int* in_sizes, int n_in,
                              void* d_out, int out_size, void* d_ws, size_t ws_size,
                              hipStream_t stream) {
    const float* z        = (const float*)d_in[0];
    const float* ln_in_w  = (const float*)d_in[1];
    const float* ln_in_b  = (const float*)d_in[2];
    const float* Wp       = (const float*)d_in[3];
    const float* Wg       = (const float*)d_in[4];
    const float* ln_out_w = (const float*)d_in[5];
    const float* ln_out_b = (const float*)d_in[6];
    const float* Wout     = (const float*)d_in[7];
    const float* Wgate    = (const float*)d_in[8];
    float* out = (float*)d_out;

    // ws layout (235,012,096 B total < 256 MiB):
    //   [0, 128K)    Wimg(73728) | W1t@81920(16384) | s1@98304(256) | s2@98560(256)
    //   [128K,+67MB) a_t ; +67MB b_t ; +33.5MB gout ; +67MB omid
    char* wsb = (char*)d_ws;
    half_t* Wimg = (half_t*)wsb;
    half_t* W1t  = (half_t*)(wsb + 81920);
    float*  s1   = (float*)(wsb + 98304);
    float*  s2   = (float*)(wsb + 98560);
    half_t* a_t  = (half_t*)(wsb + 131072);
    half_t* b_t  = a_t + (size_t)HID * ROWS;
    half_t* gout = b_t + (size_t)HID * ROWS;
    half_t* omid = gout + (size_t)ROWS * 64;

    k_prep_w<<<dim3(19), dim3(256), 0, stream>>>(Wp, Wg, Wgate, ln_out_w, ln_out_b, Wout,
                                                 Wimg, W1t, s1, s2);
    k_proj<<<dim3(ROWS / 128, 2), dim3(512), 0, stream>>>(z, ln_in_w, ln_in_b, Wimg,
                                                          a_t, b_t, gout);
    k_einsum<<<dim3(512), dim3(512), 0, stream>>>(a_t, b_t, omid);
    k_final<<<dim3(ROWS / 64), dim3(256), 0, stream>>>(omid, W1t, s1, s2, gout, out);
}

// Round 9
// 167.101 us; speedup vs baseline: 1.0919x; 1.0919x over previous
//
#include <hip/hip_runtime.h>
#include <hip/hip_fp16.h>

// TriMul (outgoing) pipeline, MI355X gfx950.
//  K0: Wimg = pre-swizzled LDS image of [Wp|Wg|Wgate] cols; W1t/s1/s2 fold LN-out
//  K1: LayerNorm(d=64) of z -> h fp16, float4 loads (h aliased into omid)
//  K2: proj GEMM h @ W^T + fast sigmoid -> a_t/b_t (k-slot PRE-SWIZZLED for K3's
//      BK=32 image: slot S holds logical s = S^((i>>1)&3)), g_out. (round-7 version)
//  K3: batched einsum C_c = A_c*B_c^T — BARRIER-FREE wave-private pipeline:
//      each wave owns a 128x64 tile + private 3-buffer LDS slice, staged via
//      global_load_lds 2 K-steps ahead, counted per-wave vmcnt (no __syncthreads
//      in the K-loop at all). XCD-grouped: each channel's 8 blocks on one XCD.
//  K4: stats + MFMA (raw mid @ W1) + affine LN correction + gate -> out fp32

typedef _Float16 half_t;
typedef _Float16 f16x4 __attribute__((ext_vector_type(4)));
typedef _Float16 f16x8 __attribute__((ext_vector_type(8)));
typedef float f32x4 __attribute__((ext_vector_type(4)));

#define NSEQ 512
#define HID 128
#define ROWS (NSEQ * NSEQ)   // 262144

#define GLOAD16(src, dst)                                                        \
    __builtin_amdgcn_global_load_lds(                                            \
        (const __attribute__((address_space(1))) void*)(src),                    \
        (__attribute__((address_space(3))) void*)(dst), 16, 0, 0)

__device__ __forceinline__ float fast_sigmoid(float x) {
    float e = __builtin_amdgcn_exp2f(-1.44269504088896f * x);
    return __builtin_amdgcn_rcpf(1.f + e);
}

// ---------------------------------------------------------------- K0: weights
__global__ void k_prep_w(const float* __restrict__ Wp, const float* __restrict__ Wg,
                         const float* __restrict__ Wgate,
                         const float* __restrict__ ln_out_w, const float* __restrict__ ln_out_b,
                         const float* __restrict__ Wout,
                         half_t* __restrict__ Wimg, half_t* __restrict__ W1t,
                         float* __restrict__ s1, float* __restrict__ s2) {
    int bid = blockIdx.x, t = threadIdx.x;
    if (bid < 18) {
        int chunk = bid * 256 + t;               // 4608 = 2 ch x 2304
        int ch = chunk >= 2304;
        int q = chunk - ch * 2304;
        int lr = q >> 3, slot = q & 7;
        int co = slot ^ (lr & 7);
        int grow;
        if (lr < 128)      grow = ch * 128 + lr;               // Wp cols
        else if (lr < 256) grow = 256 + ch * 128 + (lr - 128); // Wg cols
        else               grow = 512 + ch * 32 + (lr - 256);  // Wgate cols
        f16x8 vals;
        #pragma unroll
        for (int j = 0; j < 8; ++j) {
            int l = co * 8 + j;
            float v;
            if (grow < 256)      v = Wp[l * 256 + grow];
            else if (grow < 512) v = Wg[l * 256 + (grow - 256)];
            else                 v = Wgate[l * 64 + (grow - 512)];
            vals[j] = (half_t)v;
        }
        *(f16x8*)(Wimg + (size_t)chunk * 8) = vals;
    } else {
        // W1t[o][c] = ln_out_w[c] * Wout[c][o]   (64 x 128)
        #pragma unroll
        for (int i = 0; i < 32; ++i) {
            int idx = t * 32 + i;                // 8192
            int o = idx >> 7, c = idx & 127;
            W1t[idx] = (half_t)(ln_out_w[c] * Wout[c * 64 + o]);
        }
        if (t < 64) {
            float a1 = 0.f, a2 = 0.f;
            for (int c = 0; c < 128; ++c) {
                float wo = Wout[c * 64 + t];
                a1 += ln_out_w[c] * wo;
                a2 += ln_out_b[c] * wo;
            }
            s1[t] = a1; s2[t] = a2;
        }
    }
}

// ---------------------------------------------------------------- K1: LN(d=64)
// 16 rows/block, float4 per lane (wave reads 4 rows = 1 KB contiguous)
__global__ __launch_bounds__(256) void k_ln_in(const float* __restrict__ z,
                                               const float* __restrict__ w,
                                               const float* __restrict__ b,
                                               half_t* __restrict__ h) {
    int t = threadIdx.x;
    int row = blockIdx.x * 16 + (t >> 4);
    int c4 = t & 15;
    f32x4 x = *(const f32x4*)(z + (size_t)row * 64 + c4 * 4);
    float s = x[0] + x[1] + x[2] + x[3];
    float s2 = x[0]*x[0] + x[1]*x[1] + x[2]*x[2] + x[3]*x[3];
    #pragma unroll
    for (int off = 1; off < 16; off <<= 1) {
        s  += __shfl_xor(s,  off, 64);
        s2 += __shfl_xor(s2, off, 64);
    }
    float mu = s * (1.f / 64.f);
    float var = s2 * (1.f / 64.f) - mu * mu;
    float rs = rsqrtf(var + 1e-5f);
    f32x4 wv = *(const f32x4*)(w + c4 * 4);
    f32x4 bv = *(const f32x4*)(b + c4 * 4);
    f16x4 o;
    #pragma unroll
    for (int j = 0; j < 4; ++j)
        o[j] = (half_t)((x[j] - mu) * rs * wv[j] + bv[j]);
    *(f16x4*)(h + (size_t)row * 64 + c4 * 4) = o;
}

// ---------------------------------------------------------------- K2: projections
// grid (4096, 2): x = 64-row block, y = half (0 -> a + gate[0..31], 1 -> b + gate[32..63])
// LDS 45312 B -> 3 blocks/CU. a_t/b_t written with BK=32 k-slot swizzle
// (slot S holds logical s = S ^ ((i>>1)&3), within each 32-k tile).
__global__ __launch_bounds__(256) void k_proj(const half_t* __restrict__ h,
                                              const half_t* __restrict__ Wimg,
                                              half_t* __restrict__ a_t,
                                              half_t* __restrict__ b_t,
                                              half_t* __restrict__ g_out) {
    __shared__ half_t Wl[288 * 64];        // 36 KB, swizzled rows of 128B (image copy)
    __shared__ half_t pgl[64 * 66];        // 8448 B, [c&63][row] stride 66

    int t = threadIdx.x;
    int ch = blockIdx.y;
    int bx = blockIdx.x;
    int r0 = bx * 64;
    int wid = t >> 6, lane = t & 63;
    int m = lane & 15, g = lane >> 4;

    // stage weights via async DMA (image is pre-swizzled + linear)
    const half_t* wsrc = Wimg + (size_t)ch * 2304 * 8;
    #pragma unroll
    for (int it = 0; it < 9; ++it) {
        int cb = it * 256 + wid * 64;      // wave-uniform chunk base
        GLOAD16(wsrc + (size_t)(cb + lane) * 8, Wl + (size_t)cb * 8);
    }

    // A fragments straight from global (2 KB/wave, coalesced; h is L2/L3-hot)
    int growbase = r0 + wid * 16;
    f16x8 af[2];
    #pragma unroll
    for (int ks = 0; ks < 2; ++ks)
        af[ks] = *(const f16x8*)(h + (size_t)(growbase + m) * 64 + ks * 32 + g * 8);

    __syncthreads();   // drains gload_lds (vmcnt 0) + all waves staged

    half_t* dst = (ch == 0) ? a_t : b_t;
    int swz = (bx >> 4) & 3;               // = (i>>1)&3, i = bx>>3

    // p/g pair tiles in 2 groups of 4; pgl holds 64 channels, flushed per group
    for (int grp = 0; grp < 2; ++grp) {
        #pragma unroll
        for (int pt4 = 0; pt4 < 4; ++pt4) {
            int pt = grp * 4 + pt4;
            f32x4 accp = {0.f, 0.f, 0.f, 0.f}, accg = {0.f, 0.f, 0.f, 0.f};
            #pragma unroll
            for (int ks = 0; ks < 2; ++ks) {
                int kb = (ks * 32 + g * 8) * 2;
                int lrp = pt * 16 + m;
                f16x8 bp = *(const f16x8*)((char*)Wl + lrp * 128 + (kb ^ ((lrp & 7) << 4)));
                int lrg = 128 + pt * 16 + m;
                f16x8 bg = *(const f16x8*)((char*)Wl + lrg * 128 + (kb ^ ((lrg & 7) << 4)));
                accp = __builtin_amdgcn_mfma_f32_16x16x32_f16(af[ks], bp, accp, 0, 0, 0);
                accg = __builtin_amdgcn_mfma_f32_16x16x32_f16(af[ks], bg, accg, 0, 0, 0);
            }
            f16x4 pk;
            #pragma unroll
            for (int r = 0; r < 4; ++r)
                pk[r] = (half_t)(accp[r] * fast_sigmoid(accg[r]));
            *(f16x4*)&pgl[(pt4 * 16 + m) * 66 + wid * 16 + g * 4] = pk;
        }
        __syncthreads();
        // flush 64 channels x 64 rows; k-slot swizzled for K3's BK=32 LDS image
        #pragma unroll
        for (int it = 0; it < 2; ++it) {
            int chunk = it * 256 + t;      // 512
            int cl = chunk >> 3, r8 = chunk & 7;
            f16x8 v = *(const f16x8*)&pgl[cl * 66 + r8 * 8];
            int dk = (r8 & 4) | ((r8 & 3) ^ swz);
            *(f16x8*)(dst + (size_t)(grp * 64 + cl) * ROWS + r0 + dk * 8) = v;
        }
        __syncthreads();
    }

    // gate tiles -> g_out[row][och] = sigmoid(h @ Wgate)
    for (int gt = 0; gt < 2; ++gt) {
        f32x4 acc = {0.f, 0.f, 0.f, 0.f};
        #pragma unroll
        for (int ks = 0; ks < 2; ++ks) {
            int kb = (ks * 32 + g * 8) * 2;
            int lr = 256 + gt * 16 + m;
            f16x8 bb = *(const f16x8*)((char*)Wl + lr * 128 + (kb ^ ((lr & 7) << 4)));
            acc = __builtin_amdgcn_mfma_f32_16x16x32_f16(af[ks], bb, acc, 0, 0, 0);
        }
        int och = ch * 32 + gt * 16 + m;
        #pragma unroll
        for (int r = 0; r < 4; ++r) {
            float og = fast_sigmoid(acc[r]);
            int grow = growbase + g * 4 + r;
            g_out[(size_t)grow * 64 + och] = (half_t)og;
        }
    }
}

// ---------------------------------------------------------------- K3: batched einsum
// 1024 blocks x 256 threads. Each WAVE independently computes a 128x64 tile of
// one channel's C = A*B^T, with a PRIVATE 36 KB LDS slice (3 bufs x (A 8K + B 4K)),
// staged 2 K-steps ahead via global_load_lds + per-wave counted vmcnt.
// NO __syncthreads in the K-loop -> no lockstep, wave skew hides latency.
// Mapping: channel's 8 blocks share one XCD (bid&7), ~4 channels live per XCD
// at a time -> 4 MB working set = one L2.
__global__ __launch_bounds__(256) void k_einsum(const half_t* __restrict__ a_t,
                                                const half_t* __restrict__ b_t,
                                                half_t* __restrict__ out_mid) {
    __shared__ half_t lds[4][3][6144];   // [wave][buf][A:4096 | B:2048] = 144 KB

    int t = threadIdx.x;
    int wid = t >> 6, lane = t & 63;
    int m = lane & 15, g = lane >> 4;

    int bid = blockIdx.x;
    int xcd = bid & 7;
    int r = bid >> 3;
    int tt = r & 7, u = r >> 3;          // u in [0,16)
    int c = xcd + 8 * u;                 // channel
    int id = tt * 4 + wid;               // wave-tile id in [0,32)
    int i0 = (id >> 3) * 128, j0 = (id & 7) * 64;

    const half_t* A = a_t + (size_t)c * ROWS;   // [i][k], k-slots pre-swizzled
    const half_t* B = b_t + (size_t)c * ROWS;   // [j][k]

    f32x4 acc[8][4] = {};

    // per K-step per wave: A 128x32 (512 chunks, 8 gloads) + B 64x32 (4 gloads)
#define STAGE(ktt, bi)                                                            \
    {                                                                             \
        half_t* dA = &lds[wid][bi][0];                                            \
        half_t* dB = &lds[wid][bi][4096];                                         \
        _Pragma("unroll")                                                         \
        for (int inst = 0; inst < 8; ++inst) {                                    \
            int q = inst * 64 + lane;                                             \
            GLOAD16(A + (size_t)(i0 + (q >> 2)) * 512 + (ktt) * 32 + (q & 3) * 8, \
                    dA + (size_t)inst * 512);                                     \
        }                                                                         \
        _Pragma("unroll")                                                         \
        for (int inst = 0; inst < 4; ++inst) {                                    \
            int q = inst * 64 + lane;                                             \
            GLOAD16(B + (size_t)(j0 + (q >> 2)) * 512 + (ktt) * 32 + (q & 3) * 8, \
                    dB + (size_t)inst * 512);                                     \
        }                                                                         \
    }

    STAGE(0, 0);
    STAGE(1, 1);

    #pragma unroll
    for (int kt = 0; kt < 16; ++kt) {
        const int cur = kt % 3;
        if (kt < 14) {
            STAGE(kt + 2, (kt + 2) % 3);
            // outstanding: stage(kt,~done) 12 + stage(kt+1) 12 + stage(kt+2) 12;
            // wait until 24 remain -> stage(kt) complete, 2 tiles stay in flight
            asm volatile("s_waitcnt vmcnt(24)" ::: "memory");
        } else if (kt == 14) {
            asm volatile("s_waitcnt vmcnt(12)" ::: "memory");
        } else {
            asm volatile("s_waitcnt vmcnt(0)" ::: "memory");
        }
        __builtin_amdgcn_sched_barrier(0);

        const half_t* Ac = &lds[wid][cur][0];
        const half_t* Bc = &lds[wid][cur][4096];
        f16x8 bf[4];
        #pragma unroll
        for (int ni = 0; ni < 4; ++ni) {
            int lrow = ni * 16 + m;
            bf[ni] = *(const f16x8*)((const char*)Bc + lrow * 64 +
                                     ((g ^ ((lrow >> 1) & 3)) << 4));
        }
        #pragma unroll
        for (int mi = 0; mi < 8; ++mi) {
            int lrow = mi * 16 + m;
            f16x8 afr = *(const f16x8*)((const char*)Ac + lrow * 64 +
                                        ((g ^ ((lrow >> 1) & 3)) << 4));
            #pragma unroll
            for (int ni = 0; ni < 4; ++ni)
                acc[mi][ni] = __builtin_amdgcn_mfma_f32_16x16x32_f16(afr, bf[ni], acc[mi][ni], 0, 0, 0);
        }
    }
#undef STAGE

    half_t* O = out_mid + (size_t)c * ROWS;   // [i*512 + j]
    #pragma unroll
    for (int mi = 0; mi < 8; ++mi) {
        #pragma unroll
        for (int ni = 0; ni < 4; ++ni) {
            int row = i0 + mi * 16 + g * 4;
            int col = j0 + ni * 16 + m;
            #pragma unroll
            for (int r2 = 0; r2 < 4; ++r2)
                O[(size_t)(row + r2) * 512 + col] = (half_t)acc[mi][ni][r2];
        }
    }
}

// ---------------------------------------------------------------- K4: folded LN + MFMA + gate
// out[p,o] = (rs_p*(x@W1)[o] - mu_p*rs_p*s1[o] + s2[o]) * gate[p,o]
__global__ __launch_bounds__(256) void k_final(const half_t* __restrict__ out_mid,
                                               const half_t* __restrict__ W1t,
                                               const float* __restrict__ s1g,
                                               const float* __restrict__ s2g,
                                               const half_t* __restrict__ g_out,
                                               float* __restrict__ out) {
    __shared__ half_t midl[128 * 64];   // [c][p] 16 KB linear
    __shared__ half_t midt[64 * 128];   // [p][c] 16 KB swizzled
    __shared__ half_t w1l[64 * 128];    // [o][c] 16 KB swizzled
    __shared__ half_t gl[64 * 72];      // [p][o] 9 KB padded
    __shared__ float smu[64], srs[64], s1l[64], s2l[64];

    int t = threadIdx.x;
    int pos0 = blockIdx.x * 64;

    #pragma unroll
    for (int it = 0; it < 4; ++it) {
        int chunk = it * 256 + t;       // 1024
        int cc = chunk >> 3, co = chunk & 7;
        *(uint4*)((char*)midl + cc * 128 + co * 16) =
            *(const uint4*)(out_mid + (size_t)cc * ROWS + pos0 + co * 8);
    }
    // w1l: 64 rows x 16 slots of 16B = 1024 chunks
    #pragma unroll
    for (int it = 0; it < 4; ++it) {
        int chunk = it * 256 + t;       // 1024
        int row = chunk >> 4, slot = chunk & 15;
        *(uint4*)((char*)w1l + row * 256 + ((slot * 16) ^ ((row & 7) << 4))) =
            *(const uint4*)(W1t + row * 128 + slot * 8);
    }
    #pragma unroll
    for (int it = 0; it < 2; ++it) {
        int chunk = it * 256 + t;       // 512
        int row = chunk >> 3, co = chunk & 7;
        *(uint4*)((char*)gl + row * 144 + co * 16) =
            *(const uint4*)(g_out + (size_t)(pos0 + row) * 64 + co * 8);
    }
    if (t < 64) { s1l[t] = s1g[t]; s2l[t] = s2g[t]; }
    __syncthreads();

    // transpose midl -> midt (swizzled) + per-position stats
    {
        int p = t >> 2, q = t & 3;
        float s = 0.f, s2 = 0.f;
        #pragma unroll
        for (int cc4 = 0; cc4 < 4; ++cc4) {
            f16x8 pack;
            #pragma unroll
            for (int j = 0; j < 8; ++j) {
                half_t hv = midl[(q * 32 + cc4 * 8 + j) * 64 + p];
                float v = (float)hv;
                s += v; s2 += v * v;
                pack[j] = hv;
            }
            int slot = q * 4 + cc4;
            *(f16x8*)((char*)midt + p * 256 + ((slot * 16) ^ ((p & 7) << 4))) = pack;
        }
        s  += __shfl_xor(s, 1, 64);  s  += __shfl_xor(s, 2, 64);
        s2 += __shfl_xor(s2, 1, 64); s2 += __shfl_xor(s2, 2, 64);
        if (q == 0) {
            float mu = s * (1.f / 128.f);
            float var = s2 * (1.f / 128.f) - mu * mu;
            smu[p] = mu;
            srs[p] = rsqrtf(var + 1e-5f);
        }
    }
    __syncthreads();

    int wid = t >> 6, lane = t & 63;
    int m = lane & 15, g = lane >> 4;

    f32x4 acc[4] = {};
    #pragma unroll
    for (int ks = 0; ks < 4; ++ks) {
        int arow = wid * 16 + m;
        f16x8 af = *(const f16x8*)((char*)midt + arow * 256 +
                                   (((4 * ks + g) * 16) ^ ((arow & 7) << 4)));
        #pragma unroll
        for (int ni = 0; ni < 4; ++ni) {
            int brow = ni * 16 + m;
            f16x8 bf = *(const f16x8*)((char*)w1l + brow * 256 +
                                       (((4 * ks + g) * 16) ^ ((brow & 7) << 4)));
            acc[ni] = __builtin_amdgcn_mfma_f32_16x16x32_f16(af, bf, acc[ni], 0, 0, 0);
        }
    }

    #pragma unroll
    for (int ni = 0; ni < 4; ++ni) {
        int o = ni * 16 + m;
        float v1 = s1l[o], v2 = s2l[o];
        #pragma unroll
        for (int r = 0; r < 4; ++r) {
            int lrow = wid * 16 + g * 4 + r;
            float mu = smu[lrow], rs = srs[lrow];
            float val = acc[ni][r] * rs - mu * rs * v1 + v2;
            float gate = (float)gl[lrow * 72 + o];
            out[(size_t)(pos0 + lrow) * 64 + o] = val * gate;
        }
    }
}

// ---------------------------------------------------------------- launch
extern "C" void kernel_launch(void* const* d_in, const int* in_sizes, int n_in,
                              void* d_out, int out_size, void* d_ws, size_t ws_size,
                              hipStream_t stream) {
    const float* z        = (const float*)d_in[0];
    const float* ln_in_w  = (const float*)d_in[1];
    const float* ln_in_b  = (const float*)d_in[2];
    const float* Wp       = (const float*)d_in[3];
    const float* Wg       = (const float*)d_in[4];
    const float* ln_out_w = (const float*)d_in[5];
    const float* ln_out_b = (const float*)d_in[6];
    const float* Wout     = (const float*)d_in[7];
    const float* Wgate    = (const float*)d_in[8];
    float* out = (float*)d_out;

    // ws layout (235,012,096 B total < 256 MiB):
    //   [0, 128K)    Wimg(73728) | W1t@81920(16384) | s1@98304(256) | s2@98560(256)
    //   [128K,+67MB) a_t ; +67MB b_t ; +33.5MB gout ; +67MB omid (h aliases omid)
    char* wsb = (char*)d_ws;
    half_t* Wimg = (half_t*)wsb;
    half_t* W1t  = (half_t*)(wsb + 81920);
    float*  s1   = (float*)(wsb + 98304);
    float*  s2   = (float*)(wsb + 98560);
    half_t* a_t  = (half_t*)(wsb + 131072);
    half_t* b_t  = a_t + (size_t)HID * ROWS;
    half_t* gout = b_t + (size_t)HID * ROWS;
    half_t* omid = gout + (size_t)ROWS * 64;
    half_t* h    = omid;   // aliased: h consumed by K2, omid produced by K3

    k_prep_w<<<dim3(19), dim3(256), 0, stream>>>(Wp, Wg, Wgate, ln_out_w, ln_out_b, Wout,
                                                 Wimg, W1t, s1, s2);
    k_ln_in<<<dim3(ROWS / 16), dim3(256), 0, stream>>>(z, ln_in_w, ln_in_b, h);
    k_proj<<<dim3(ROWS / 64, 2), dim3(256), 0, stream>>>(h, Wimg, a_t, b_t, gout);
    k_einsum<<<dim3(1024), dim3(256), 0, stream>>>(a_t, b_t, omid);
    k_final<<<dim3(ROWS / 64), dim3(256), 0, stream>>>(omid, W1t, s1, s2, gout, out);
}

// Round 10
// 157.126 us; speedup vs baseline: 1.1612x; 1.0635x over previous
//
#include <hip/hip_runtime.h>
#include <hip/hip_fp16.h>

// TriMul (outgoing) pipeline, MI355X gfx950.
//  K0: Wimg = pre-swizzled LDS image of [Wp|Wg|Wgate] cols; W1t/s1/s2 fold LN-out
//  K1: LayerNorm(d=64) of z -> h fp16, float4 loads (h aliased into omid)
//  K2: proj GEMM h @ W^T + fast sigmoid -> a_t/b_t (k-slot PRE-SWIZZLED, round-7)
//  K3: batched einsum C_c = A_c*B_c^T — 256-thread blocks (4 waves, 256x128 tile),
//      2 blocks/CU (independent barrier domains), 3 K-tile LDS buffers, 2-K-tile
//      prefetch lead, counted vmcnt(6), per-K-step single barrier, stage loads
//      interleaved between quadrant MFMA bursts, setprio around MFMA.
//  K4: stats + MFMA (raw mid @ W1) + affine LN correction + gate -> out fp32

typedef _Float16 half_t;
typedef _Float16 f16x4 __attribute__((ext_vector_type(4)));
typedef _Float16 f16x8 __attribute__((ext_vector_type(8)));
typedef float f32x4 __attribute__((ext_vector_type(4)));

#define NSEQ 512
#define HID 128
#define ROWS (NSEQ * NSEQ)   // 262144

#define GLOAD16(src, dst)                                                        \
    __builtin_amdgcn_global_load_lds(                                            \
        (const __attribute__((address_space(1))) void*)(src),                    \
        (__attribute__((address_space(3))) void*)(dst), 16, 0, 0)

__device__ __forceinline__ float fast_sigmoid(float x) {
    float e = __builtin_amdgcn_exp2f(-1.44269504088896f * x);
    return __builtin_amdgcn_rcpf(1.f + e);
}

// ---------------------------------------------------------------- K0: weights
__global__ void k_prep_w(const float* __restrict__ Wp, const float* __restrict__ Wg,
                         const float* __restrict__ Wgate,
                         const float* __restrict__ ln_out_w, const float* __restrict__ ln_out_b,
                         const float* __restrict__ Wout,
                         half_t* __restrict__ Wimg, half_t* __restrict__ W1t,
                         float* __restrict__ s1, float* __restrict__ s2) {
    int bid = blockIdx.x, t = threadIdx.x;
    if (bid < 18) {
        int chunk = bid * 256 + t;               // 4608 = 2 ch x 2304
        int ch = chunk >= 2304;
        int q = chunk - ch * 2304;
        int lr = q >> 3, slot = q & 7;
        int co = slot ^ (lr & 7);
        int grow;
        if (lr < 128)      grow = ch * 128 + lr;               // Wp cols
        else if (lr < 256) grow = 256 + ch * 128 + (lr - 128); // Wg cols
        else               grow = 512 + ch * 32 + (lr - 256);  // Wgate cols
        f16x8 vals;
        #pragma unroll
        for (int j = 0; j < 8; ++j) {
            int l = co * 8 + j;
            float v;
            if (grow < 256)      v = Wp[l * 256 + grow];
            else if (grow < 512) v = Wg[l * 256 + (grow - 256)];
            else                 v = Wgate[l * 64 + (grow - 512)];
            vals[j] = (half_t)v;
        }
        *(f16x8*)(Wimg + (size_t)chunk * 8) = vals;
    } else {
        // W1t[o][c] = ln_out_w[c] * Wout[c][o]   (64 x 128)
        #pragma unroll
        for (int i = 0; i < 32; ++i) {
            int idx = t * 32 + i;                // 8192
            int o = idx >> 7, c = idx & 127;
            W1t[idx] = (half_t)(ln_out_w[c] * Wout[c * 64 + o]);
        }
        if (t < 64) {
            float a1 = 0.f, a2 = 0.f;
            for (int c = 0; c < 128; ++c) {
                float wo = Wout[c * 64 + t];
                a1 += ln_out_w[c] * wo;
                a2 += ln_out_b[c] * wo;
            }
            s1[t] = a1; s2[t] = a2;
        }
    }
}

// ---------------------------------------------------------------- K1: LN(d=64)
__global__ __launch_bounds__(256) void k_ln_in(const float* __restrict__ z,
                                               const float* __restrict__ w,
                                               const float* __restrict__ b,
                                               half_t* __restrict__ h) {
    int t = threadIdx.x;
    int row = blockIdx.x * 16 + (t >> 4);
    int c4 = t & 15;
    f32x4 x = *(const f32x4*)(z + (size_t)row * 64 + c4 * 4);
    float s = x[0] + x[1] + x[2] + x[3];
    float s2 = x[0]*x[0] + x[1]*x[1] + x[2]*x[2] + x[3]*x[3];
    #pragma unroll
    for (int off = 1; off < 16; off <<= 1) {
        s  += __shfl_xor(s,  off, 64);
        s2 += __shfl_xor(s2, off, 64);
    }
    float mu = s * (1.f / 64.f);
    float var = s2 * (1.f / 64.f) - mu * mu;
    float rs = rsqrtf(var + 1e-5f);
    f32x4 wv = *(const f32x4*)(w + c4 * 4);
    f32x4 bv = *(const f32x4*)(b + c4 * 4);
    f16x4 o;
    #pragma unroll
    for (int j = 0; j < 4; ++j)
        o[j] = (half_t)((x[j] - mu) * rs * wv[j] + bv[j]);
    *(f16x4*)(h + (size_t)row * 64 + c4 * 4) = o;
}

// ---------------------------------------------------------------- K2: projections
// grid (4096, 2): x = 64-row block, y = half (0 -> a + gate[0..31], 1 -> b + gate[32..63])
// LDS 45312 B -> 3 blocks/CU. a_t/b_t written with BK=32 k-slot swizzle
// (slot S holds logical s = S ^ ((i>>1)&3), within each 32-k tile).
__global__ __launch_bounds__(256) void k_proj(const half_t* __restrict__ h,
                                              const half_t* __restrict__ Wimg,
                                              half_t* __restrict__ a_t,
                                              half_t* __restrict__ b_t,
                                              half_t* __restrict__ g_out) {
    __shared__ half_t Wl[288 * 64];        // 36 KB, swizzled rows of 128B (image copy)
    __shared__ half_t pgl[64 * 66];        // 8448 B, [c&63][row] stride 66

    int t = threadIdx.x;
    int ch = blockIdx.y;
    int bx = blockIdx.x;
    int r0 = bx * 64;
    int wid = t >> 6, lane = t & 63;
    int m = lane & 15, g = lane >> 4;

    // stage weights via async DMA (image is pre-swizzled + linear)
    const half_t* wsrc = Wimg + (size_t)ch * 2304 * 8;
    #pragma unroll
    for (int it = 0; it < 9; ++it) {
        int cb = it * 256 + wid * 64;      // wave-uniform chunk base
        GLOAD16(wsrc + (size_t)(cb + lane) * 8, Wl + (size_t)cb * 8);
    }

    // A fragments straight from global (2 KB/wave, coalesced; h is L2/L3-hot)
    int growbase = r0 + wid * 16;
    f16x8 af[2];
    #pragma unroll
    for (int ks = 0; ks < 2; ++ks)
        af[ks] = *(const f16x8*)(h + (size_t)(growbase + m) * 64 + ks * 32 + g * 8);

    __syncthreads();   // drains gload_lds (vmcnt 0) + all waves staged

    half_t* dst = (ch == 0) ? a_t : b_t;
    int swz = (bx >> 4) & 3;               // = (i>>1)&3, i = bx>>3

    // p/g pair tiles in 2 groups of 4; pgl holds 64 channels, flushed per group
    for (int grp = 0; grp < 2; ++grp) {
        #pragma unroll
        for (int pt4 = 0; pt4 < 4; ++pt4) {
            int pt = grp * 4 + pt4;
            f32x4 accp = {0.f, 0.f, 0.f, 0.f}, accg = {0.f, 0.f, 0.f, 0.f};
            #pragma unroll
            for (int ks = 0; ks < 2; ++ks) {
                int kb = (ks * 32 + g * 8) * 2;
                int lrp = pt * 16 + m;
                f16x8 bp = *(const f16x8*)((char*)Wl + lrp * 128 + (kb ^ ((lrp & 7) << 4)));
                int lrg = 128 + pt * 16 + m;
                f16x8 bg = *(const f16x8*)((char*)Wl + lrg * 128 + (kb ^ ((lrg & 7) << 4)));
                accp = __builtin_amdgcn_mfma_f32_16x16x32_f16(af[ks], bp, accp, 0, 0, 0);
                accg = __builtin_amdgcn_mfma_f32_16x16x32_f16(af[ks], bg, accg, 0, 0, 0);
            }
            f16x4 pk;
            #pragma unroll
            for (int r = 0; r < 4; ++r)
                pk[r] = (half_t)(accp[r] * fast_sigmoid(accg[r]));
            *(f16x4*)&pgl[(pt4 * 16 + m) * 66 + wid * 16 + g * 4] = pk;
        }
        __syncthreads();
        // flush 64 channels x 64 rows; k-slot swizzled for K3's BK=32 LDS image
        #pragma unroll
        for (int it = 0; it < 2; ++it) {
            int chunk = it * 256 + t;      // 512
            int cl = chunk >> 3, r8 = chunk & 7;
            f16x8 v = *(const f16x8*)&pgl[cl * 66 + r8 * 8];
            int dk = (r8 & 4) | ((r8 & 3) ^ swz);
            *(f16x8*)(dst + (size_t)(grp * 64 + cl) * ROWS + r0 + dk * 8) = v;
        }
        __syncthreads();
    }

    // gate tiles -> g_out[row][och] = sigmoid(h @ Wgate)
    for (int gt = 0; gt < 2; ++gt) {
        f32x4 acc = {0.f, 0.f, 0.f, 0.f};
        #pragma unroll
        for (int ks = 0; ks < 2; ++ks) {
            int kb = (ks * 32 + g * 8) * 2;
            int lr = 256 + gt * 16 + m;
            f16x8 bb = *(const f16x8*)((char*)Wl + lr * 128 + (kb ^ ((lr & 7) << 4)));
            acc = __builtin_amdgcn_mfma_f32_16x16x32_f16(af[ks], bb, acc, 0, 0, 0);
        }
        int och = ch * 32 + gt * 16 + m;
        #pragma unroll
        for (int r = 0; r < 4; ++r) {
            float og = fast_sigmoid(acc[r]);
            int grow = growbase + g * 4 + r;
            g_out[(size_t)grow * 64 + och] = (half_t)og;
        }
    }
}

// ---------------------------------------------------------------- K3: batched einsum
// 1024 blocks x 256 threads (4 waves), tile 256x128, 2 blocks/CU.
// 3 K-tile LDS buffers (A 256x32 + B 128x32 = 24 KB each, 72 KB total).
// Stage K(t+2) while computing K(t): counted vmcnt(6) = one K-tile (6 loads)
// allowed outstanding; single barrier per K-step; stage loads interleaved
// between the 4 quadrant MFMA bursts. LDS read XOR: slot = g ^ ((row>>1)&3).
#define BUFH 12288   // halves per buffer (24 KB); A at 0, B at 8192
__global__ __launch_bounds__(256, 2) void k_einsum(const half_t* __restrict__ a_t,
                                                   const half_t* __restrict__ b_t,
                                                   half_t* __restrict__ out_mid) {
    __shared__ half_t lds[3 * BUFH];   // 72 KB

    int t = threadIdx.x;
    int wid = t >> 6, lane = t & 63;
    int m = lane & 15, g = lane >> 4;

    int bid = blockIdx.x;
    int xcd = bid & 7;
    int idx = bid >> 3;                  // [0,128)
    int c = xcd + 8 * (idx >> 3);        // channel: 8 blocks of a channel on one XCD
    int tt = idx & 7;
    int i0 = (tt & 1) * 256, j0 = (tt >> 1) * 128;

    const half_t* A = a_t + (size_t)c * ROWS;   // [i][k], k-slots pre-swizzled
    const half_t* B = b_t + (size_t)c * ROWS;   // [j][k]

    int wr = wid >> 1, wc = wid & 1;            // wave tile: 128 rows x 64 cols

    f32x4 acc[8][4] = {};

    // per K-step per thread: A 4 loads (256x32), B 2 loads (128x32) -> vmcnt quantum 6
#define STAGE_A(ktt, base, it)                                                    \
    {                                                                             \
        int cb = (it) * 256 + wid * 64;      /* wave-uniform chunk base */        \
        int chunk = cb + lane;                                                    \
        GLOAD16(A + (size_t)(i0 + (chunk >> 2)) * 512 + (ktt) * 32 + (chunk & 3) * 8, \
                (base) + (size_t)cb * 8);                                         \
    }
#define STAGE_B(ktt, base, it)                                                    \
    {                                                                             \
        int cb = (it) * 256 + wid * 64;                                           \
        int chunk = cb + lane;                                                    \
        GLOAD16(B + (size_t)(j0 + (chunk >> 2)) * 512 + (ktt) * 32 + (chunk & 3) * 8, \
                (base) + 8192 + (size_t)cb * 8);                                  \
    }
#define STAGE_ALL(ktt, base)                                                      \
    STAGE_A(ktt, base, 0) STAGE_A(ktt, base, 1) STAGE_A(ktt, base, 2)             \
    STAGE_A(ktt, base, 3) STAGE_B(ktt, base, 0) STAGE_B(ktt, base, 1)

    STAGE_ALL(0, lds)
    STAGE_ALL(1, lds + BUFH)

    #pragma unroll
    for (int kt = 0; kt < 16; ++kt) {
        const half_t* Ac = lds + (kt % 3) * BUFH;
        const half_t* Bc = Ac + 8192;
        half_t* nxt = lds + ((kt + 2) % 3) * BUFH;

        // K(t) resident; K(t+1)'s 6 loads may remain in flight
        if (kt <= 14) asm volatile("s_waitcnt vmcnt(6)" ::: "memory");
        else          asm volatile("s_waitcnt vmcnt(0)" ::: "memory");
        __builtin_amdgcn_s_barrier();            // all waves' K(t) landed; buf(t+2)%3 free
        __builtin_amdgcn_sched_barrier(0);

        // B fragments once per K-step
        f16x8 bf[4];
        #pragma unroll
        for (int ni = 0; ni < 4; ++ni) {
            int lrow = wc * 64 + ni * 16 + m;
            bf[ni] = *(const f16x8*)((const char*)Bc + lrow * 64 +
                                     ((g ^ ((lrow >> 1) & 3)) << 4));
        }

        #pragma unroll
        for (int q = 0; q < 4; ++q) {
            int lr0 = wr * 128 + (q * 2) * 16 + m;
            int lr1 = lr0 + 16;
            f16x8 af0 = *(const f16x8*)((const char*)Ac + lr0 * 64 +
                                        ((g ^ ((lr0 >> 1) & 3)) << 4));
            f16x8 af1 = *(const f16x8*)((const char*)Ac + lr1 * 64 +
                                        ((g ^ ((lr1 >> 1) & 3)) << 4));
            if (kt < 14) {                       // interleave next+2 stage issues
                if (q == 0)      { STAGE_A(kt + 2, nxt, 0) STAGE_A(kt + 2, nxt, 1) }
                else if (q == 1) { STAGE_A(kt + 2, nxt, 2) STAGE_A(kt + 2, nxt, 3) }
                else if (q == 2) { STAGE_B(kt + 2, nxt, 0) }
                else             { STAGE_B(kt + 2, nxt, 1) }
            }
            __builtin_amdgcn_s_setprio(1);
            #pragma unroll
            for (int ni = 0; ni < 4; ++ni) {
                acc[q * 2][ni]     = __builtin_amdgcn_mfma_f32_16x16x32_f16(af0, bf[ni], acc[q * 2][ni], 0, 0, 0);
                acc[q * 2 + 1][ni] = __builtin_amdgcn_mfma_f32_16x16x32_f16(af1, bf[ni], acc[q * 2 + 1][ni], 0, 0, 0);
            }
            __builtin_amdgcn_s_setprio(0);
        }
    }
#undef STAGE_ALL
#undef STAGE_B
#undef STAGE_A

    half_t* O = out_mid + (size_t)c * ROWS;   // [i*512 + j]
    #pragma unroll
    for (int mi = 0; mi < 8; ++mi) {
        #pragma unroll
        for (int ni = 0; ni < 4; ++ni) {
            int row = i0 + wr * 128 + mi * 16 + g * 4;
            int col = j0 + wc * 64 + ni * 16 + m;
            #pragma unroll
            for (int r2 = 0; r2 < 4; ++r2)
                O[(size_t)(row + r2) * 512 + col] = (half_t)acc[mi][ni][r2];
        }
    }
}

// ---------------------------------------------------------------- K4: folded LN + MFMA + gate
// out[p,o] = (rs_p*(x@W1)[o] - mu_p*rs_p*s1[o] + s2[o]) * gate[p,o]
__global__ __launch_bounds__(256) void k_final(const half_t* __restrict__ out_mid,
                                               const half_t* __restrict__ W1t,
                                               const float* __restrict__ s1g,
                                               const float* __restrict__ s2g,
                                               const half_t* __restrict__ g_out,
                                               float* __restrict__ out) {
    __shared__ half_t midl[128 * 64];   // [c][p] 16 KB linear
    __shared__ half_t midt[64 * 128];   // [p][c] 16 KB swizzled
    __shared__ half_t w1l[64 * 128];    // [o][c] 16 KB swizzled
    __shared__ half_t gl[64 * 72];      // [p][o] 9 KB padded
    __shared__ float smu[64], srs[64], s1l[64], s2l[64];

    int t = threadIdx.x;
    int pos0 = blockIdx.x * 64;

    #pragma unroll
    for (int it = 0; it < 4; ++it) {
        int chunk = it * 256 + t;       // 1024
        int cc = chunk >> 3, co = chunk & 7;
        *(uint4*)((char*)midl + cc * 128 + co * 16) =
            *(const uint4*)(out_mid + (size_t)cc * ROWS + pos0 + co * 8);
    }
    // w1l: 64 rows x 16 slots of 16B = 1024 chunks
    #pragma unroll
    for (int it = 0; it < 4; ++it) {
        int chunk = it * 256 + t;       // 1024
        int row = chunk >> 4, slot = chunk & 15;
        *(uint4*)((char*)w1l + row * 256 + ((slot * 16) ^ ((row & 7) << 4))) =
            *(const uint4*)(W1t + row * 128 + slot * 8);
    }
    #pragma unroll
    for (int it = 0; it < 2; ++it) {
        int chunk = it * 256 + t;       // 512
        int row = chunk >> 3, co = chunk & 7;
        *(uint4*)((char*)gl + row * 144 + co * 16) =
            *(const uint4*)(g_out + (size_t)(pos0 + row) * 64 + co * 8);
    }
    if (t < 64) { s1l[t] = s1g[t]; s2l[t] = s2g[t]; }
    __syncthreads();

    // transpose midl -> midt (swizzled) + per-position stats
    {
        int p = t >> 2, q = t & 3;
        float s = 0.f, s2 = 0.f;
        #pragma unroll
        for (int cc4 = 0; cc4 < 4; ++cc4) {
            f16x8 pack;
            #pragma unroll
            for (int j = 0; j < 8; ++j) {
                half_t hv = midl[(q * 32 + cc4 * 8 + j) * 64 + p];
                float v = (float)hv;
                s += v; s2 += v * v;
                pack[j] = hv;
            }
            int slot = q * 4 + cc4;
            *(f16x8*)((char*)midt + p * 256 + ((slot * 16) ^ ((p & 7) << 4))) = pack;
        }
        s  += __shfl_xor(s, 1, 64);  s  += __shfl_xor(s, 2, 64);
        s2 += __shfl_xor(s2, 1, 64); s2 += __shfl_xor(s2, 2, 64);
        if (q == 0) {
            float mu = s * (1.f / 128.f);
            float var = s2 * (1.f / 128.f) - mu * mu;
            smu[p] = mu;
            srs[p] = rsqrtf(var + 1e-5f);
        }
    }
    __syncthreads();

    int wid = t >> 6, lane = t & 63;
    int m = lane & 15, g = lane >> 4;

    f32x4 acc[4] = {};
    #pragma unroll
    for (int ks = 0; ks < 4; ++ks) {
        int arow = wid * 16 + m;
        f16x8 af = *(const f16x8*)((char*)midt + arow * 256 +
                                   (((4 * ks + g) * 16) ^ ((arow & 7) << 4)));
        #pragma unroll
        for (int ni = 0; ni < 4; ++ni) {
            int brow = ni * 16 + m;
            f16x8 bf = *(const f16x8*)((char*)w1l + brow * 256 +
                                       (((4 * ks + g) * 16) ^ ((brow & 7) << 4)));
            acc[ni] = __builtin_amdgcn_mfma_f32_16x16x32_f16(af, bf, acc[ni], 0, 0, 0);
        }
    }

    #pragma unroll
    for (int ni = 0; ni < 4; ++ni) {
        int o = ni * 16 + m;
        float v1 = s1l[o], v2 = s2l[o];
        #pragma unroll
        for (int r = 0; r < 4; ++r) {
            int lrow = wid * 16 + g * 4 + r;
            float mu = smu[lrow], rs = srs[lrow];
            float val = acc[ni][r] * rs - mu * rs * v1 + v2;
            float gate = (float)gl[lrow * 72 + o];
            out[(size_t)(pos0 + lrow) * 64 + o] = val * gate;
        }
    }
}

// ---------------------------------------------------------------- launch
extern "C" void kernel_launch(void* const* d_in, const int* in_sizes, int n_in,
                              void* d_out, int out_size, void* d_ws, size_t ws_size,
                              hipStream_t stream) {
    const float* z        = (const float*)d_in[0];
    const float* ln_in_w  = (const float*)d_in[1];
    const float* ln_in_b  = (const float*)d_in[2];
    const float* Wp       = (const float*)d_in[3];
    const float* Wg       = (const float*)d_in[4];
    const float* ln_out_w = (const float*)d_in[5];
    const float* ln_out_b = (const float*)d_in[6];
    const float* Wout     = (const float*)d_in[7];
    const float* Wgate    = (const float*)d_in[8];
    float* out = (float*)d_out;

    // ws layout (235,012,096 B total < 256 MiB):
    //   [0, 128K)    Wimg(73728) | W1t@81920(16384) | s1@98304(256) | s2@98560(256)
    //   [128K,+67MB) a_t ; +67MB b_t ; +33.5MB gout ; +67MB omid (h aliases omid)
    char* wsb = (char*)d_ws;
    half_t* Wimg = (half_t*)wsb;
    half_t* W1t  = (half_t*)(wsb + 81920);
    float*  s1   = (float*)(wsb + 98304);
    float*  s2   = (float*)(wsb + 98560);
    half_t* a_t  = (half_t*)(wsb + 131072);
    half_t* b_t  = a_t + (size_t)HID * ROWS;
    half_t* gout = b_t + (size_t)HID * ROWS;
    half_t* omid = gout + (size_t)ROWS * 64;
    half_t* h    = omid;   // aliased: h consumed by K2, omid produced by K3

    k_prep_w<<<dim3(19), dim3(256), 0, stream>>>(Wp, Wg, Wgate, ln_out_w, ln_out_b, Wout,
                                                 Wimg, W1t, s1, s2);
    k_ln_in<<<dim3(ROWS / 16), dim3(256), 0, stream>>>(z, ln_in_w, ln_in_b, h);
    k_proj<<<dim3(ROWS / 64, 2), dim3(256), 0, stream>>>(h, Wimg, a_t, b_t, gout);
    k_einsum<<<dim3(1024), dim3(256), 0, stream>>>(a_t, b_t, omid);
    k_final<<<dim3(ROWS / 64), dim3(256), 0, stream>>>(omid, W1t, s1, s2, gout, out);
}